// Round 10
// baseline (276419.360 us; speedup 1.0000x reference)
//
#include <hip/hip_runtime.h>
#include <hip/hip_fp16.h>
#include <hip/hip_bf16.h>

#define TSTEPS 1019
#define BATCH 8
#define CIN 4
#define LEN 524288
#define COUT 512
#define HID 512
#define KERN 3072
#define CSTRIDE 512
#define KTOT (CIN * KERN)          // 12288
#define MROWS (TSTEPS * BATCH)     // 8152

typedef _Float16 half2_v __attribute__((ext_vector_type(2)));
typedef __attribute__((ext_vector_type(8))) short bf16x8;
typedef __attribute__((ext_vector_type(4))) float f32x4;
typedef unsigned long long u64;

#if defined(__has_builtin)
#if __has_builtin(__builtin_amdgcn_fdot2)
#define HAVE_FDOT2 1
#endif
#endif

__device__ __forceinline__ float dot2f(__half2 a, __half2 b, float c) {
#ifdef HAVE_FDOT2
    return __builtin_amdgcn_fdot2(__builtin_bit_cast(half2_v, a),
                                  __builtin_bit_cast(half2_v, b), c, false);
#else
    float2 af = __half22float2(a), bf = __half22float2(b);
    return fmaf(af.y, bf.y, fmaf(af.x, bf.x, c));
#endif
}

struct __align__(16) H2x4 { __half2 x, y, z, w; };

__device__ __forceinline__ short bfc(float x) {
    return (short)__builtin_bit_cast(unsigned short, __float2bfloat16(x));
}

__device__ __forceinline__ void load_lds16(const unsigned short* g, unsigned short* l) {
    __builtin_amdgcn_global_load_lds(
        (const __attribute__((address_space(1))) void*)g,
        (__attribute__((address_space(3))) void*)l, 16, 0, 0);
}

// L1-bypassing load: served by the CU's XCD L2 when the line is resident there.
__device__ __forceinline__ u64 load_fast(const u64* p) {
    u64 v;
    asm volatile("global_load_dwordx2 %0, %1, off sc0\n\t"
                 "s_waitcnt vmcnt(0)"
                 : "=v"(v) : "v"(p) : "memory");
    return v;
}
// Plain store: lands (dirty) in the producer's XCD L2 — the fast channel.
__device__ __forceinline__ void store_plain(u64* p, u64 v) {
    asm volatile("global_store_dwordx2 %0, %1, off" :: "v"(p), "v"(v) : "memory");
}

// ---------------------------------------------------------------------------
// fp32 -> bf16 convert (unchanged)
// ---------------------------------------------------------------------------
__global__ __launch_bounds__(256) void f2bf_k(
        const float* __restrict__ a, unsigned short* __restrict__ o, int n4) {
    int i = blockIdx.x * blockDim.x + threadIdx.x;
    int stride = gridDim.x * blockDim.x;
    for (; i < n4; i += stride) {
        float4 f = reinterpret_cast<const float4*>(a)[i];
        ushort4 u;
        u.x = (unsigned short)bfc(f.x); u.y = (unsigned short)bfc(f.y);
        u.z = (unsigned short)bfc(f.z); u.w = (unsigned short)bfc(f.w);
        reinterpret_cast<ushort4*>(o)[i] = u;
    }
}

// ---------------------------------------------------------------------------
// Conv1d implicit GEMM on MFMA (unchanged from round 4)
// ---------------------------------------------------------------------------
__global__ __launch_bounds__(256, 2) void conv_mfma_k(
        const float* __restrict__ in, const unsigned short* __restrict__ wb,
        const float* __restrict__ bias, unsigned short* __restrict__ out) {
    __shared__ unsigned short At[2][128 * 64];
    __shared__ unsigned short Bt[2][128 * 64];
    const int m0 = blockIdx.y * 128;
    const int n0 = blockIdx.x * 128;
    const int tid = threadIdx.x;
    const int w = tid >> 6, l = tid & 63;
    const int wm = w >> 1, wn = w & 1;
    const int fr = l & 15, fq = l >> 4;

    const int ra = tid >> 1, hh = tid & 1;
    int mA = m0 + ra; if (mA > MROWS - 1) mA = MROWS - 1;
    const int tA = mA >> 3, bA = mA & 7;

    f32x4 acc[4][4] = {};
    const int NT = KTOT / 64;

    {
        const float* src = in + (size_t)(bA * CIN + 0) * LEN
                              + (size_t)tA * CSTRIDE + 0 + hh * 32;
        #pragma unroll
        for (int cc = 0; cc < 4; ++cc) {
            float4 f0 = reinterpret_cast<const float4*>(src)[cc * 2];
            float4 f1 = reinterpret_cast<const float4*>(src)[cc * 2 + 1];
            bf16x8 v;
            v[0] = bfc(f0.x); v[1] = bfc(f0.y); v[2] = bfc(f0.z); v[3] = bfc(f0.w);
            v[4] = bfc(f1.x); v[5] = bfc(f1.y); v[6] = bfc(f1.z); v[7] = bfc(f1.w);
            const int c = hh * 4 + cc, s = c ^ (ra & 7);
            *reinterpret_cast<bf16x8*>(&At[0][ra * 64 + s * 8]) = v;
        }
        #pragma unroll
        for (int i = 0; i < 4; ++i) {
            const int rb = w * 32 + i * 8 + (l >> 3);
            const int s = l & 7, c = s ^ (rb & 7);
            load_lds16(wb + (size_t)(n0 + rb) * KTOT + 0 + c * 8,
                       &Bt[0][(w * 32 + i * 8) * 64]);
        }
    }
    __syncthreads();

    int cur = 0;
    for (int t = 0; t < NT; ++t) {
        const int nxt = cur ^ 1;
        float4 fA[8];
        const bool more = (t + 1 < NT);
        if (more) {
            const int k0 = (t + 1) * 64;
            const int ci = k0 / KERN, kr = k0 - ci * KERN;
            const float* src = in + (size_t)(bA * CIN + ci) * LEN
                                  + (size_t)tA * CSTRIDE + kr + hh * 32;
            #pragma unroll
            for (int v = 0; v < 8; ++v)
                fA[v] = reinterpret_cast<const float4*>(src)[v];
            #pragma unroll
            for (int i = 0; i < 4; ++i) {
                const int rb = w * 32 + i * 8 + (l >> 3);
                const int s = l & 7, c = s ^ (rb & 7);
                load_lds16(wb + (size_t)(n0 + rb) * KTOT + k0 + c * 8,
                           &Bt[nxt][(w * 32 + i * 8) * 64]);
            }
        }
        #pragma unroll
        for (int ks = 0; ks < 2; ++ks) {
            bf16x8 af[4], bfg[4];
            #pragma unroll
            for (int mf = 0; mf < 4; ++mf) {
                const int rA = wm * 64 + mf * 16 + fr;
                const int cw = ks * 4 + fq, s = cw ^ (rA & 7);
                af[mf] = *reinterpret_cast<const bf16x8*>(&At[cur][rA * 64 + s * 8]);
            }
            #pragma unroll
            for (int nf = 0; nf < 4; ++nf) {
                const int rB = wn * 64 + nf * 16 + fr;
                const int cw = ks * 4 + fq, s = cw ^ (rB & 7);
                bfg[nf] = *reinterpret_cast<const bf16x8*>(&Bt[cur][rB * 64 + s * 8]);
            }
            #pragma unroll
            for (int mf = 0; mf < 4; ++mf)
                #pragma unroll
                for (int nf = 0; nf < 4; ++nf)
                    acc[mf][nf] = __builtin_amdgcn_mfma_f32_16x16x32_bf16(
                        af[mf], bfg[nf], acc[mf][nf], 0, 0, 0);
        }
        if (more) {
            #pragma unroll
            for (int cc = 0; cc < 4; ++cc) {
                float4 f0 = fA[cc * 2], f1 = fA[cc * 2 + 1];
                bf16x8 v;
                v[0] = bfc(f0.x); v[1] = bfc(f0.y); v[2] = bfc(f0.z); v[3] = bfc(f0.w);
                v[4] = bfc(f1.x); v[5] = bfc(f1.y); v[6] = bfc(f1.z); v[7] = bfc(f1.w);
                const int c = hh * 4 + cc, s = c ^ (ra & 7);
                *reinterpret_cast<bf16x8*>(&At[nxt][ra * 64 + s * 8]) = v;
            }
        }
        __syncthreads();
        cur = nxt;
    }

    #pragma unroll
    for (int nf = 0; nf < 4; ++nf) {
        const int n = n0 + wn * 64 + nf * 16 + fr;
        const float bv = bias[n];
        #pragma unroll
        for (int mf = 0; mf < 4; ++mf) {
            #pragma unroll
            for (int i = 0; i < 4; ++i) {
                const int m = m0 + wm * 64 + mf * 16 + fq * 4 + i;
                if (m < MROWS)
                    out[(size_t)m * COUT + n] =
                        (unsigned short)bfc(acc[mf][nf][i] + bv);
            }
        }
    }
}

// ---------------------------------------------------------------------------
// gi projection MFMA (unchanged from round 4)
// ---------------------------------------------------------------------------
__global__ __launch_bounds__(256, 2) void proj_mfma_k(
        const unsigned short* __restrict__ A, const unsigned short* __restrict__ wb,
        const float* __restrict__ bias, float* __restrict__ out) {
    __shared__ unsigned short At[2][128 * 64];
    __shared__ unsigned short Bt[2][128 * 64];
    const int m0 = blockIdx.y * 128;
    const int n0 = blockIdx.x * 128;
    const int tid = threadIdx.x;
    const int w = tid >> 6, l = tid & 63;
    const int wm = w >> 1, wn = w & 1;
    const int fr = l & 15, fq = l >> 4;

    f32x4 acc[4][4] = {};
    const int NT = COUT / 64;

    auto stage = [&](int buf, int k0) {
        #pragma unroll
        for (int i = 0; i < 4; ++i) {
            const int r = w * 32 + i * 8 + (l >> 3);
            const int s = l & 7, c = s ^ (r & 7);
            int mA = m0 + r; if (mA > MROWS - 1) mA = MROWS - 1;
            load_lds16(A + (size_t)mA * COUT + k0 + c * 8,
                       &At[buf][(w * 32 + i * 8) * 64]);
            load_lds16(wb + (size_t)(n0 + r) * COUT + k0 + c * 8,
                       &Bt[buf][(w * 32 + i * 8) * 64]);
        }
    };

    stage(0, 0);
    __syncthreads();
    int cur = 0;
    for (int t = 0; t < NT; ++t) {
        const int nxt = cur ^ 1;
        if (t + 1 < NT) stage(nxt, (t + 1) * 64);
        #pragma unroll
        for (int ks = 0; ks < 2; ++ks) {
            bf16x8 af[4], bfg[4];
            #pragma unroll
            for (int mf = 0; mf < 4; ++mf) {
                const int rA = wm * 64 + mf * 16 + fr;
                const int cw = ks * 4 + fq, s = cw ^ (rA & 7);
                af[mf] = *reinterpret_cast<const bf16x8*>(&At[cur][rA * 64 + s * 8]);
            }
            #pragma unroll
            for (int nf = 0; nf < 4; ++nf) {
                const int rB = wn * 64 + nf * 16 + fr;
                const int cw = ks * 4 + fq, s = cw ^ (rB & 7);
                bfg[nf] = *reinterpret_cast<const bf16x8*>(&Bt[cur][rB * 64 + s * 8]);
            }
            #pragma unroll
            for (int mf = 0; mf < 4; ++mf)
                #pragma unroll
                for (int nf = 0; nf < 4; ++nf)
                    acc[mf][nf] = __builtin_amdgcn_mfma_f32_16x16x32_bf16(
                        af[mf], bfg[nf], acc[mf][nf], 0, 0, 0);
        }
        __syncthreads();
        cur = nxt;
    }

    #pragma unroll
    for (int nf = 0; nf < 4; ++nf) {
        const int n = n0 + wn * 64 + nf * 16 + fr;
        const float bv = bias[n];
        #pragma unroll
        for (int mf = 0; mf < 4; ++mf) {
            #pragma unroll
            for (int i = 0; i < 4; ++i) {
                const int m = m0 + wm * 64 + mf * 16 + fq * 4 + i;
                if (m < MROWS)
                    out[(size_t)m * 1536 + n] = acc[mf][nf][i] + bv;
            }
        }
    }
}

// ---------------------------------------------------------------------------
// GRU scan, round 10 = round 9 + XCD-aware fast exchange.
// Prologue: (1) every block registers its REAL XCD (s_getreg HW_REG_XCC_ID)
// in a device-scope registry; blocks are ranked by (xcd, bid) and rank ->
// (batch=rank/4, slice=rank%4), so teams land on one XCD when dispatch
// round-robins (correct under ANY mapping). (2) One probe round on the
// actual fast channel (plain store -> sc0 load) decides fast/slow per
// polling thread — ground truth, not an assumption.
// Scan: round-9 body. Producers publish {epoch:32|2xfp16:32} words twice:
// plain store (same-L2 fast channel) + relaxed agent store (MALL,
// authoritative). Fast pollers spin on the L2 word with a 1-in-2048-spin
// slow-buffer check (no deadlock even on a false-positive probe); slow
// pollers = round-9 proven loop. Parity double-buffer + exact-epoch match:
// deadlock/overwrite proof unchanged from round 3.
// ---------------------------------------------------------------------------
__global__ __launch_bounds__(512, 1) void gru_scan_k(
        const float* __restrict__ gi, const float* __restrict__ w_hh,
        const float* __restrict__ b_hh, const float* __restrict__ hidden,
        float* __restrict__ out, u64* __restrict__ h_ex) {
    const int bid = blockIdx.x;
    const int tid = threadIdx.x;
    const int wv  = tid >> 6;          // wave 0..7
    const int l   = tid & 63;
    const int q   = wv >> 1;           // k-quarter this wave-pair consumes
    const int g   = (wv & 1) * 64 + l; // row-in-block 0..127

    u64* hfast  = h_ex;                // [2][8][256] L2 fast channel
    u64* hslow  = h_ex + 4096;         // [2][8][256] MALL authoritative
    u64* probeF = h_ex + 8192;         // [8][256] probe words
    int* regs   = (int*)(h_ex + 10240);// [33]: xcd+1 per block, counter

    __shared__ __align__(16) __half2 strip[8][64];
    __shared__ float p_lds[3 * 128 * 5];
    __shared__ int lflag[2];
    __shared__ int s_role[2];

    // ---- registration: real XCD id -> rank -> (batch, slice) ----
    int my_xcd;
    asm volatile("s_getreg_b32 %0, hwreg(20, 0, 32)" : "=s"(my_xcd)); // HW_REG_XCC_ID
    my_xcd &= 0xf;
    if (tid == 0) {
        __hip_atomic_store(&regs[bid], my_xcd + 1, __ATOMIC_RELAXED,
                           __HIP_MEMORY_SCOPE_AGENT);
        __hip_atomic_fetch_add(&regs[32], 1, __ATOMIC_ACQ_REL,
                               __HIP_MEMORY_SCOPE_AGENT);
        while (__hip_atomic_load(&regs[32], __ATOMIC_ACQUIRE,
                                 __HIP_MEMORY_SCOPE_AGENT) < 32)
            __builtin_amdgcn_s_sleep(2);
        int key[32];
        for (int i = 0; i < 32; ++i) {
            int x;
            do {
                x = __hip_atomic_load(&regs[i], __ATOMIC_RELAXED,
                                      __HIP_MEMORY_SCOPE_AGENT);
            } while (x == 0);
            key[i] = x * 64 + i;
        }
        const int me = key[bid];
        int rank = 0;
        for (int i = 0; i < 32; ++i) rank += (key[i] < me);
        s_role[0] = rank >> 2;       // batch
        s_role[1] = rank & 3;        // slice
    }
    __syncthreads();
    const int b   = s_role[0];
    const int isl = s_role[1];
    const int j   = isl * 128 + g;     // h row this thread computes (quarter q)
    const bool is_gate = (q == isl);

    // ---- probe the fast channel (ground truth, once per launch) ----
    const u64 PROBE = 0x7FFF000000000000ULL;
    if (tid < 64)
        store_plain(&probeF[(size_t)b * 256 + isl * 64 + tid], PROBE);
    bool fast_ok = false;
    if (!is_gate) {
        const u64* pp = &probeF[(size_t)b * 256 + q * 64 + l];
        for (int it = 0; it < 256; ++it) {
            if (load_fast(pp) == PROBE) { fast_ok = true; break; }
        }
    }

    // ---- weights: 3 gates x 128 k (quarter q) of row j -> 192 half2 ----
    __half2 wreg[3][64];
    #pragma unroll
    for (int m = 0; m < 3; ++m) {
        const float* wp = w_hh + (size_t)(j + m * 512) * HID + q * 128;
        #pragma unroll
        for (int kk = 0; kk < 32; ++kk) {
            float4 v = reinterpret_cast<const float4*>(wp)[kk];
            wreg[m][2 * kk]     = __halves2half2(__float2half_rn(v.x), __float2half_rn(v.y));
            wreg[m][2 * kk + 1] = __halves2half2(__float2half_rn(v.z), __float2half_rn(v.w));
        }
    }

    float bhr = 0.f, bhz = 0.f, bhn = 0.f, hprev = 0.f;
    float gir = 0.f, giz = 0.f, gin = 0.f;
    if (is_gate) {
        bhr = b_hh[j]; bhz = b_hh[j + 512]; bhn = b_hh[j + 1024];
        hprev = hidden[b * HID + j];
        gir = gi[(size_t)b * 1536 + j];
        giz = gi[(size_t)b * 1536 + j + 512];
        gin = gi[(size_t)b * 1536 + j + 1024];
    }
    if (tid < 2) lflag[tid] = 0;
    strip[wv][l] = __halves2half2(__float2half(hidden[b * HID + q * 128 + 2 * l]),
                                  __float2half(hidden[b * HID + q * 128 + 2 * l + 1]));
    __syncthreads();

    for (int t = 0; t < TSTEPS; ++t) {
        // ---- acquire epoch t (t>0) ----
        if (t > 0) {
            if (!is_gate) {
                const size_t idx = (size_t)((t & 1) * BATCH + b) * 256 + q * 64 + l;
                u64 v;
                if (fast_ok) {
                    const u64* pf = &hfast[idx];
                    const u64* ps = &hslow[idx];
                    int spins = 0;
                    for (;;) {
                        v = load_fast(pf);
                        if ((unsigned)(v >> 32) == (unsigned)t) break;
                        if (((++spins) & 2047) == 0) {
                            v = __hip_atomic_load(ps, __ATOMIC_RELAXED,
                                                  __HIP_MEMORY_SCOPE_AGENT);
                            if ((unsigned)(v >> 32) == (unsigned)t) break;
                        }
                    }
                } else {
                    const u64* ps = &hslow[idx];
                    do {
                        v = __hip_atomic_load(ps, __ATOMIC_RELAXED,
                                              __HIP_MEMORY_SCOPE_AGENT);
                    } while ((unsigned)(v >> 32) != (unsigned)t);
                }
                strip[wv][l] = __builtin_bit_cast(__half2, (unsigned)(v & 0xffffffffu));
                asm volatile("s_waitcnt lgkmcnt(0)" ::: "memory");
            } else {
                volatile int* f0 = &lflag[0];
                volatile int* f1 = &lflag[1];
                while (*f0 < t || *f1 < t) {}
                asm volatile("" ::: "memory");
            }
        }
        // ---- matvec over quarter q from the wave's strip ----
        const H2x4* hv4 = reinterpret_cast<const H2x4*>(&strip[wv][0]);
        float a0 = 0, a1 = 0, a2 = 0, c0 = 0, c1 = 0, c2 = 0;
        #pragma unroll
        for (int kk = 0; kk < 16; ++kk) {
            H2x4 h4 = hv4[kk];
            a0 = dot2f(wreg[0][4 * kk + 0], h4.x, a0);
            a1 = dot2f(wreg[1][4 * kk + 0], h4.x, a1);
            a2 = dot2f(wreg[2][4 * kk + 0], h4.x, a2);
            c0 = dot2f(wreg[0][4 * kk + 1], h4.y, c0);
            c1 = dot2f(wreg[1][4 * kk + 1], h4.y, c1);
            c2 = dot2f(wreg[2][4 * kk + 1], h4.y, c2);
            a0 = dot2f(wreg[0][4 * kk + 2], h4.z, a0);
            a1 = dot2f(wreg[1][4 * kk + 2], h4.z, a1);
            a2 = dot2f(wreg[2][4 * kk + 2], h4.z, a2);
            c0 = dot2f(wreg[0][4 * kk + 3], h4.w, c0);
            c1 = dot2f(wreg[1][4 * kk + 3], h4.w, c1);
            c2 = dot2f(wreg[2][4 * kk + 3], h4.w, c2);
        }
        p_lds[(0 * 128 + g) * 5 + q] = a0 + c0;
        p_lds[(1 * 128 + g) * 5 + q] = a1 + c1;
        p_lds[(2 * 128 + g) * 5 + q] = a2 + c2;
        __syncthreads();   // the ONLY barrier per step

        // ---- gates by pair isl; remote pairs fall through to next poll ----
        if (is_gate) {
            const float* pr = &p_lds[(0 * 128 + g) * 5];
            const float* pz = &p_lds[(1 * 128 + g) * 5];
            const float* pn = &p_lds[(2 * 128 + g) * 5];
            const float ghr = (pr[0] + pr[1]) + (pr[2] + pr[3]) + bhr;
            const float ghz = (pz[0] + pz[1]) + (pz[2] + pz[3]) + bhz;
            const float ghn = (pn[0] + pn[1]) + (pn[2] + pn[3]) + bhn;
            const float rr = 1.f / (1.f + __expf(-(gir + ghr)));
            const float zz = 1.f / (1.f + __expf(-(giz + ghz)));
            const float nx = gin + rr * ghn;
            const float nn = 1.f - 2.f / (__expf(2.f * nx) + 1.f);   // tanh
            const float hnew = (1.f - zz) * nn + zz * hprev;
            hprev = hnew;
            const float hother = __shfl_xor(hnew, 1);
            if (t + 1 < TSTEPS) {
                if (!(g & 1)) {
                    const __half2 h2 = __halves2half2(__float2half(hnew),
                                                      __float2half(hother));
                    const u64 v =
                        ((u64)(unsigned)(t + 1) << 32) |
                        (u64)__builtin_bit_cast(unsigned, h2);
                    const size_t idx =
                        (size_t)(((t + 1) & 1) * BATCH + b) * 256
                        + isl * 64 + (g >> 1);
                    store_plain(&hfast[idx], v);                   // L2 channel
                    __hip_atomic_store(&hslow[idx], v, __ATOMIC_RELAXED,
                                       __HIP_MEMORY_SCOPE_AGENT);  // authoritative
                    strip[2 * isl][g >> 1] = h2;
                    strip[2 * isl + 1][g >> 1] = h2;
                }
                asm volatile("s_waitcnt lgkmcnt(0)" ::: "memory");
                if (l == 0) lflag[wv & 1] = t + 1;
                out[(size_t)(t * BATCH + b) * HID + j] = hnew;
                const float* gp = gi + (size_t)((t + 1) * BATCH + b) * 1536 + j;
                gir = gp[0]; giz = gp[512]; gin = gp[1024];
            } else {
                out[(size_t)(t * BATCH + b) * HID + j] = hnew;
            }
        }
    }
    if (is_gate)
        out[(size_t)TSTEPS * BATCH * HID + b * HID + j] = hprev;
}

extern "C" void kernel_launch(void* const* d_in, const int* in_sizes, int n_in,
                              void* d_out, int out_size, void* d_ws, size_t ws_size,
                              hipStream_t stream) {
    (void)in_sizes; (void)n_in; (void)out_size; (void)ws_size;
    const float* input  = (const float*)d_in[0];
    const float* hidden = (const float*)d_in[1];
    const float* conv_w = (const float*)d_in[2];
    const float* conv_b = (const float*)d_in[3];
    const float* w_ih   = (const float*)d_in[4];
    const float* w_hh   = (const float*)d_in[5];
    const float* b_ih   = (const float*)d_in[6];
    const float* b_hh   = (const float*)d_in[7];
    float* out = (float*)d_out;

    char* ws = (char*)d_ws;
    float*          gi       = (float*)ws;                          // 50,085,888 B
    unsigned short* conv_out = (unsigned short*)(ws + 50085888);    //  8,347,648 B
    unsigned short* w_bf     = (unsigned short*)(ws + 58433536);    // 12,582,912 B
    unsigned short* wih_bf   = (unsigned short*)(ws + 71016448);    //  1,572,864 B
    u64*            h_ex     = (u64*)(ws + 72589312);               //     82,948 B
    // h_ex layout: hfast 32768 | hslow 32768 | probe 16384 | regs 132

    f2bf_k<<<2048, 256, 0, stream>>>(conv_w, w_bf, KTOT * COUT / 4);
    f2bf_k<<<768, 256, 0, stream>>>(w_ih, wih_bf, 1536 * COUT / 4);

    dim3 cgrid(4, 64);
    conv_mfma_k<<<cgrid, 256, 0, stream>>>(input, w_bf, conv_b, conv_out);

    dim3 pgrid(12, 64);
    proj_mfma_k<<<pgrid, 256, 0, stream>>>(conv_out, wih_bf, b_ih, gi);

    // reset exchange buffers + probe + registry each launch
    hipMemsetAsync(h_ex, 0, 84992, stream);

    gru_scan_k<<<32, 512, 0, stream>>>(gi, w_hh, b_hh, hidden, out, h_ex);
}

// Round 11
// 2991.251 us; speedup vs baseline: 92.4093x; 92.4093x over previous
//
#include <hip/hip_runtime.h>
#include <hip/hip_fp16.h>
#include <hip/hip_bf16.h>

#define TSTEPS 1019
#define BATCH 8
#define CIN 4
#define LEN 524288
#define COUT 512
#define HID 512
#define KERN 3072
#define CSTRIDE 512
#define KTOT (CIN * KERN)          // 12288
#define MROWS (TSTEPS * BATCH)     // 8152

typedef _Float16 half2_v __attribute__((ext_vector_type(2)));
typedef __attribute__((ext_vector_type(8))) short bf16x8;
typedef __attribute__((ext_vector_type(4))) float f32x4;
typedef unsigned long long u64;

#if defined(__has_builtin)
#if __has_builtin(__builtin_amdgcn_fdot2)
#define HAVE_FDOT2 1
#endif
#endif

__device__ __forceinline__ float dot2f(__half2 a, __half2 b, float c) {
#ifdef HAVE_FDOT2
    return __builtin_amdgcn_fdot2(__builtin_bit_cast(half2_v, a),
                                  __builtin_bit_cast(half2_v, b), c, false);
#else
    float2 af = __half22float2(a), bf = __half22float2(b);
    return fmaf(af.y, bf.y, fmaf(af.x, bf.x, c));
#endif
}

struct __align__(16) H2x4 { __half2 x, y, z, w; };

__device__ __forceinline__ short bfc(float x) {
    return (short)__builtin_bit_cast(unsigned short, __float2bfloat16(x));
}

__device__ __forceinline__ void load_lds16(const unsigned short* g, unsigned short* l) {
    __builtin_amdgcn_global_load_lds(
        (const __attribute__((address_space(1))) void*)g,
        (__attribute__((address_space(3))) void*)l, 16, 0, 0);
}

__device__ __forceinline__ u64 aload(const u64* p) {
    return __hip_atomic_load(p, __ATOMIC_RELAXED, __HIP_MEMORY_SCOPE_AGENT);
}

// ---------------------------------------------------------------------------
// fp32 -> bf16 convert (unchanged)
// ---------------------------------------------------------------------------
__global__ __launch_bounds__(256) void f2bf_k(
        const float* __restrict__ a, unsigned short* __restrict__ o, int n4) {
    int i = blockIdx.x * blockDim.x + threadIdx.x;
    int stride = gridDim.x * blockDim.x;
    for (; i < n4; i += stride) {
        float4 f = reinterpret_cast<const float4*>(a)[i];
        ushort4 u;
        u.x = (unsigned short)bfc(f.x); u.y = (unsigned short)bfc(f.y);
        u.z = (unsigned short)bfc(f.z); u.w = (unsigned short)bfc(f.w);
        reinterpret_cast<ushort4*>(o)[i] = u;
    }
}

// ---------------------------------------------------------------------------
// Conv1d implicit GEMM on MFMA (unchanged from round 4)
// ---------------------------------------------------------------------------
__global__ __launch_bounds__(256, 2) void conv_mfma_k(
        const float* __restrict__ in, const unsigned short* __restrict__ wb,
        const float* __restrict__ bias, unsigned short* __restrict__ out) {
    __shared__ unsigned short At[2][128 * 64];
    __shared__ unsigned short Bt[2][128 * 64];
    const int m0 = blockIdx.y * 128;
    const int n0 = blockIdx.x * 128;
    const int tid = threadIdx.x;
    const int w = tid >> 6, l = tid & 63;
    const int wm = w >> 1, wn = w & 1;
    const int fr = l & 15, fq = l >> 4;

    const int ra = tid >> 1, hh = tid & 1;
    int mA = m0 + ra; if (mA > MROWS - 1) mA = MROWS - 1;
    const int tA = mA >> 3, bA = mA & 7;

    f32x4 acc[4][4] = {};
    const int NT = KTOT / 64;

    {
        const float* src = in + (size_t)(bA * CIN + 0) * LEN
                              + (size_t)tA * CSTRIDE + 0 + hh * 32;
        #pragma unroll
        for (int cc = 0; cc < 4; ++cc) {
            float4 f0 = reinterpret_cast<const float4*>(src)[cc * 2];
            float4 f1 = reinterpret_cast<const float4*>(src)[cc * 2 + 1];
            bf16x8 v;
            v[0] = bfc(f0.x); v[1] = bfc(f0.y); v[2] = bfc(f0.z); v[3] = bfc(f0.w);
            v[4] = bfc(f1.x); v[5] = bfc(f1.y); v[6] = bfc(f1.z); v[7] = bfc(f1.w);
            const int c = hh * 4 + cc, s = c ^ (ra & 7);
            *reinterpret_cast<bf16x8*>(&At[0][ra * 64 + s * 8]) = v;
        }
        #pragma unroll
        for (int i = 0; i < 4; ++i) {
            const int rb = w * 32 + i * 8 + (l >> 3);
            const int s = l & 7, c = s ^ (rb & 7);
            load_lds16(wb + (size_t)(n0 + rb) * KTOT + 0 + c * 8,
                       &Bt[0][(w * 32 + i * 8) * 64]);
        }
    }
    __syncthreads();

    int cur = 0;
    for (int t = 0; t < NT; ++t) {
        const int nxt = cur ^ 1;
        float4 fA[8];
        const bool more = (t + 1 < NT);
        if (more) {
            const int k0 = (t + 1) * 64;
            const int ci = k0 / KERN, kr = k0 - ci * KERN;
            const float* src = in + (size_t)(bA * CIN + ci) * LEN
                                  + (size_t)tA * CSTRIDE + kr + hh * 32;
            #pragma unroll
            for (int v = 0; v < 8; ++v)
                fA[v] = reinterpret_cast<const float4*>(src)[v];
            #pragma unroll
            for (int i = 0; i < 4; ++i) {
                const int rb = w * 32 + i * 8 + (l >> 3);
                const int s = l & 7, c = s ^ (rb & 7);
                load_lds16(wb + (size_t)(n0 + rb) * KTOT + k0 + c * 8,
                           &Bt[nxt][(w * 32 + i * 8) * 64]);
            }
        }
        #pragma unroll
        for (int ks = 0; ks < 2; ++ks) {
            bf16x8 af[4], bfg[4];
            #pragma unroll
            for (int mf = 0; mf < 4; ++mf) {
                const int rA = wm * 64 + mf * 16 + fr;
                const int cw = ks * 4 + fq, s = cw ^ (rA & 7);
                af[mf] = *reinterpret_cast<const bf16x8*>(&At[cur][rA * 64 + s * 8]);
            }
            #pragma unroll
            for (int nf = 0; nf < 4; ++nf) {
                const int rB = wn * 64 + nf * 16 + fr;
                const int cw = ks * 4 + fq, s = cw ^ (rB & 7);
                bfg[nf] = *reinterpret_cast<const bf16x8*>(&Bt[cur][rB * 64 + s * 8]);
            }
            #pragma unroll
            for (int mf = 0; mf < 4; ++mf)
                #pragma unroll
                for (int nf = 0; nf < 4; ++nf)
                    acc[mf][nf] = __builtin_amdgcn_mfma_f32_16x16x32_bf16(
                        af[mf], bfg[nf], acc[mf][nf], 0, 0, 0);
        }
        if (more) {
            #pragma unroll
            for (int cc = 0; cc < 4; ++cc) {
                float4 f0 = fA[cc * 2], f1 = fA[cc * 2 + 1];
                bf16x8 v;
                v[0] = bfc(f0.x); v[1] = bfc(f0.y); v[2] = bfc(f0.z); v[3] = bfc(f0.w);
                v[4] = bfc(f1.x); v[5] = bfc(f1.y); v[6] = bfc(f1.z); v[7] = bfc(f1.w);
                const int c = hh * 4 + cc, s = c ^ (ra & 7);
                *reinterpret_cast<bf16x8*>(&At[nxt][ra * 64 + s * 8]) = v;
            }
        }
        __syncthreads();
        cur = nxt;
    }

    #pragma unroll
    for (int nf = 0; nf < 4; ++nf) {
        const int n = n0 + wn * 64 + nf * 16 + fr;
        const float bv = bias[n];
        #pragma unroll
        for (int mf = 0; mf < 4; ++mf) {
            #pragma unroll
            for (int i = 0; i < 4; ++i) {
                const int m = m0 + wm * 64 + mf * 16 + fq * 4 + i;
                if (m < MROWS)
                    out[(size_t)m * COUT + n] =
                        (unsigned short)bfc(acc[mf][nf][i] + bv);
            }
        }
    }
}

// ---------------------------------------------------------------------------
// gi projection MFMA (unchanged from round 4)
// ---------------------------------------------------------------------------
__global__ __launch_bounds__(256, 2) void proj_mfma_k(
        const unsigned short* __restrict__ A, const unsigned short* __restrict__ wb,
        const float* __restrict__ bias, float* __restrict__ out) {
    __shared__ unsigned short At[2][128 * 64];
    __shared__ unsigned short Bt[2][128 * 64];
    const int m0 = blockIdx.y * 128;
    const int n0 = blockIdx.x * 128;
    const int tid = threadIdx.x;
    const int w = tid >> 6, l = tid & 63;
    const int wm = w >> 1, wn = w & 1;
    const int fr = l & 15, fq = l >> 4;

    f32x4 acc[4][4] = {};
    const int NT = COUT / 64;

    auto stage = [&](int buf, int k0) {
        #pragma unroll
        for (int i = 0; i < 4; ++i) {
            const int r = w * 32 + i * 8 + (l >> 3);
            const int s = l & 7, c = s ^ (r & 7);
            int mA = m0 + r; if (mA > MROWS - 1) mA = MROWS - 1;
            load_lds16(A + (size_t)mA * COUT + k0 + c * 8,
                       &At[buf][(w * 32 + i * 8) * 64]);
            load_lds16(wb + (size_t)(n0 + r) * COUT + k0 + c * 8,
                       &Bt[buf][(w * 32 + i * 8) * 64]);
        }
    };

    stage(0, 0);
    __syncthreads();
    int cur = 0;
    for (int t = 0; t < NT; ++t) {
        const int nxt = cur ^ 1;
        if (t + 1 < NT) stage(nxt, (t + 1) * 64);
        #pragma unroll
        for (int ks = 0; ks < 2; ++ks) {
            bf16x8 af[4], bfg[4];
            #pragma unroll
            for (int mf = 0; mf < 4; ++mf) {
                const int rA = wm * 64 + mf * 16 + fr;
                const int cw = ks * 4 + fq, s = cw ^ (rA & 7);
                af[mf] = *reinterpret_cast<const bf16x8*>(&At[cur][rA * 64 + s * 8]);
            }
            #pragma unroll
            for (int nf = 0; nf < 4; ++nf) {
                const int rB = wn * 64 + nf * 16 + fr;
                const int cw = ks * 4 + fq, s = cw ^ (rB & 7);
                bfg[nf] = *reinterpret_cast<const bf16x8*>(&Bt[cur][rB * 64 + s * 8]);
            }
            #pragma unroll
            for (int mf = 0; mf < 4; ++mf)
                #pragma unroll
                for (int nf = 0; nf < 4; ++nf)
                    acc[mf][nf] = __builtin_amdgcn_mfma_f32_16x16x32_bf16(
                        af[mf], bfg[nf], acc[mf][nf], 0, 0, 0);
        }
        __syncthreads();
        cur = nxt;
    }

    #pragma unroll
    for (int nf = 0; nf < 4; ++nf) {
        const int n = n0 + wn * 64 + nf * 16 + fr;
        const float bv = bias[n];
        #pragma unroll
        for (int mf = 0; mf < 4; ++mf) {
            #pragma unroll
            for (int i = 0; i < 4; ++i) {
                const int m = m0 + wm * 64 + mf * 16 + fq * 4 + i;
                if (m < MROWS)
                    out[(size_t)m * 1536 + n] = acc[mf][nf][i] + bv;
            }
        }
    }
}

// ---------------------------------------------------------------------------
// GRU scan, round 11 = round 9 (proven, 1620 us) + rolling 8-deep poll.
// Topology: 8 teams x 4 slice-blocks. Wave-pair q owns k-quarter q: polls the
// 64 words it consumes into a wave-private LDS strip (lgkmcnt orders within
// wave), then matvec. Gate duty = pair q==isl (locally-produced quarter).
// ONE __syncthreads per step (anti-hazard proof: a pair writes p_lds for
// step t+1 only after acquiring epoch t+1, which requires own gates to have
// published t+1, which happens after they read p_lds for t).
// Exchange: relaxed agent-scope {epoch:32|2xfp16:32} store, exact-epoch poll,
// parity double-buffer (round-3 deadlock proof). NEW: the poll keeps 8
// relaxed agent loads in flight (check oldest, reissue) — same memory path,
// sampling interval ~RT/8 instead of ~RT. Same-address relaxed atomic loads
// respect coherence order, so exact-match on any slot is safe; worst case
// the compiler serializes and we get round-9 behavior.
// ---------------------------------------------------------------------------
__global__ __launch_bounds__(512, 1) void gru_scan_k(
        const float* __restrict__ gi, const float* __restrict__ w_hh,
        const float* __restrict__ b_hh, const float* __restrict__ hidden,
        float* __restrict__ out, u64* __restrict__ h_ex) {
    const int bid = blockIdx.x;
    const int b   = bid & 7;           // team/batch
    const int isl = bid >> 3;          // slice: block owns rows isl*128..+128
    const int tid = threadIdx.x;
    const int wv  = tid >> 6;          // wave 0..7
    const int l   = tid & 63;
    const int q   = wv >> 1;           // k-quarter this wave-pair consumes
    const int g   = (wv & 1) * 64 + l; // row-in-block 0..127
    const int j   = isl * 128 + g;     // h row this thread computes (quarter q)
    const bool is_gate = (q == isl);

    __shared__ __align__(16) __half2 strip[8][64];  // per-wave h-quarter copy
    __shared__ float p_lds[3 * 128 * 5];            // partials, stride 5
    __shared__ int lflag[2];                        // gate-wave epoch flags

    // weights: 3 gates x 128 k (quarter q) of row j -> 192 half2
    __half2 wreg[3][64];
    #pragma unroll
    for (int m = 0; m < 3; ++m) {
        const float* wp = w_hh + (size_t)(j + m * 512) * HID + q * 128;
        #pragma unroll
        for (int kk = 0; kk < 32; ++kk) {
            float4 v = reinterpret_cast<const float4*>(wp)[kk];
            wreg[m][2 * kk]     = __halves2half2(__float2half_rn(v.x), __float2half_rn(v.y));
            wreg[m][2 * kk + 1] = __halves2half2(__float2half_rn(v.z), __float2half_rn(v.w));
        }
    }

    float bhr = 0.f, bhz = 0.f, bhn = 0.f, hprev = 0.f;
    float gir = 0.f, giz = 0.f, gin = 0.f;
    if (is_gate) {
        bhr = b_hh[j]; bhz = b_hh[j + 512]; bhn = b_hh[j + 1024];
        hprev = hidden[b * HID + j];
        gir = gi[(size_t)b * 1536 + j];
        giz = gi[(size_t)b * 1536 + j + 512];
        gin = gi[(size_t)b * 1536 + j + 1024];
    }
    if (tid < 2) lflag[tid] = 0;
    // prologue: every wave fills its own strip with h_0 (epoch 0, local)
    strip[wv][l] = __halves2half2(__float2half(hidden[b * HID + q * 128 + 2 * l]),
                                  __float2half(hidden[b * HID + q * 128 + 2 * l + 1]));
    __syncthreads();

    for (int t = 0; t < TSTEPS; ++t) {
        // ---- acquire epoch t (t>0): pair-owned, no cross-wave sync ----
        if (t > 0) {
            if (!is_gate) {
                const u64* src =
                    h_ex + (size_t)((t & 1) * BATCH + b) * 256 + q * 64 + l;
                const unsigned want = (unsigned)t;
                u64 v;
                // rolling 8-deep poll: 8 relaxed agent loads in flight,
                // check oldest, reissue. Sampling interval ~RT/8.
                {
                    u64 r0 = aload(src), r1 = aload(src), r2 = aload(src),
                        r3 = aload(src), r4 = aload(src), r5 = aload(src),
                        r6 = aload(src), r7 = aload(src);
                    for (;;) {
                        if ((unsigned)(r0 >> 32) == want) { v = r0; break; }
                        r0 = aload(src);
                        if ((unsigned)(r1 >> 32) == want) { v = r1; break; }
                        r1 = aload(src);
                        if ((unsigned)(r2 >> 32) == want) { v = r2; break; }
                        r2 = aload(src);
                        if ((unsigned)(r3 >> 32) == want) { v = r3; break; }
                        r3 = aload(src);
                        if ((unsigned)(r4 >> 32) == want) { v = r4; break; }
                        r4 = aload(src);
                        if ((unsigned)(r5 >> 32) == want) { v = r5; break; }
                        r5 = aload(src);
                        if ((unsigned)(r6 >> 32) == want) { v = r6; break; }
                        r6 = aload(src);
                        if ((unsigned)(r7 >> 32) == want) { v = r7; break; }
                        r7 = aload(src);
                    }
                }
                strip[wv][l] =
                    __builtin_bit_cast(__half2, (unsigned)(v & 0xffffffffu));
                asm volatile("s_waitcnt lgkmcnt(0)" ::: "memory");
            } else {
                volatile int* f0 = &lflag[0];
                volatile int* f1 = &lflag[1];
                while (*f0 < t || *f1 < t) {}
                asm volatile("" ::: "memory");
            }
        }
        // ---- matvec over quarter q from the wave's strip (broadcast b128) ----
        const H2x4* hv4 = reinterpret_cast<const H2x4*>(&strip[wv][0]);
        float a0 = 0, a1 = 0, a2 = 0, c0 = 0, c1 = 0, c2 = 0;
        #pragma unroll
        for (int kk = 0; kk < 16; ++kk) {
            H2x4 h4 = hv4[kk];
            a0 = dot2f(wreg[0][4 * kk + 0], h4.x, a0);
            a1 = dot2f(wreg[1][4 * kk + 0], h4.x, a1);
            a2 = dot2f(wreg[2][4 * kk + 0], h4.x, a2);
            c0 = dot2f(wreg[0][4 * kk + 1], h4.y, c0);
            c1 = dot2f(wreg[1][4 * kk + 1], h4.y, c1);
            c2 = dot2f(wreg[2][4 * kk + 1], h4.y, c2);
            a0 = dot2f(wreg[0][4 * kk + 2], h4.z, a0);
            a1 = dot2f(wreg[1][4 * kk + 2], h4.z, a1);
            a2 = dot2f(wreg[2][4 * kk + 2], h4.z, a2);
            c0 = dot2f(wreg[0][4 * kk + 3], h4.w, c0);
            c1 = dot2f(wreg[1][4 * kk + 3], h4.w, c1);
            c2 = dot2f(wreg[2][4 * kk + 3], h4.w, c2);
        }
        p_lds[(0 * 128 + g) * 5 + q] = a0 + c0;   // stride 5: conflict-free
        p_lds[(1 * 128 + g) * 5 + q] = a1 + c1;
        p_lds[(2 * 128 + g) * 5 + q] = a2 + c2;
        __syncthreads();   // B1 (the ONLY barrier per step)

        // ---- gates by pair isl; remote pairs fall through and poll t+1 ----
        if (is_gate) {
            const float* pr = &p_lds[(0 * 128 + g) * 5];
            const float* pz = &p_lds[(1 * 128 + g) * 5];
            const float* pn = &p_lds[(2 * 128 + g) * 5];
            const float ghr = (pr[0] + pr[1]) + (pr[2] + pr[3]) + bhr;
            const float ghz = (pz[0] + pz[1]) + (pz[2] + pz[3]) + bhz;
            const float ghn = (pn[0] + pn[1]) + (pn[2] + pn[3]) + bhn;
            const float rr = 1.f / (1.f + __expf(-(gir + ghr)));
            const float zz = 1.f / (1.f + __expf(-(giz + ghz)));
            const float nx = gin + rr * ghn;
            const float nn = 1.f - 2.f / (__expf(2.f * nx) + 1.f);   // tanh
            const float hnew = (1.f - zz) * nn + zz * hprev;
            hprev = hnew;
            const float hother = __shfl_xor(hnew, 1);
            if (t + 1 < TSTEPS) {
                if (!(g & 1)) {
                    const __half2 h2 = __halves2half2(__float2half(hnew),
                                                      __float2half(hother));
                    const u64 v =
                        ((u64)(unsigned)(t + 1) << 32) |
                        (u64)__builtin_bit_cast(unsigned, h2);
                    // publish first (remote consumers' RT is the bottleneck)
                    __hip_atomic_store(
                        h_ex + (size_t)(((t + 1) & 1) * BATCH + b) * 256
                             + isl * 64 + (g >> 1),
                        v, __ATOMIC_RELAXED, __HIP_MEMORY_SCOPE_AGENT);
                    // local handoff for next step's own-quarter matvec
                    strip[2 * isl][g >> 1] = h2;
                    strip[2 * isl + 1][g >> 1] = h2;
                }
                asm volatile("s_waitcnt lgkmcnt(0)" ::: "memory");
                if (l == 0) lflag[wv & 1] = t + 1;   // per-gate-wave flag
                out[(size_t)(t * BATCH + b) * HID + j] = hnew;
                const float* gp = gi + (size_t)((t + 1) * BATCH + b) * 1536 + j;
                gir = gp[0]; giz = gp[512]; gin = gp[1024];
            } else {
                out[(size_t)(t * BATCH + b) * HID + j] = hnew;
            }
        }
        // no second barrier: see header comment for the anti-hazard proof
    }
    if (is_gate)
        out[(size_t)TSTEPS * BATCH * HID + b * HID + j] = hprev;
}

extern "C" void kernel_launch(void* const* d_in, const int* in_sizes, int n_in,
                              void* d_out, int out_size, void* d_ws, size_t ws_size,
                              hipStream_t stream) {
    (void)in_sizes; (void)n_in; (void)out_size; (void)ws_size;
    const float* input  = (const float*)d_in[0];
    const float* hidden = (const float*)d_in[1];
    const float* conv_w = (const float*)d_in[2];
    const float* conv_b = (const float*)d_in[3];
    const float* w_ih   = (const float*)d_in[4];
    const float* w_hh   = (const float*)d_in[5];
    const float* b_ih   = (const float*)d_in[6];
    const float* b_hh   = (const float*)d_in[7];
    float* out = (float*)d_out;

    char* ws = (char*)d_ws;
    float*          gi       = (float*)ws;                          // 50,085,888 B
    unsigned short* conv_out = (unsigned short*)(ws + 50085888);    //  8,347,648 B
    unsigned short* w_bf     = (unsigned short*)(ws + 58433536);    // 12,582,912 B
    unsigned short* wih_bf   = (unsigned short*)(ws + 71016448);    //  1,572,864 B
    u64*            h_ex     = (u64*)(ws + 72589312);               //     32,768 B

    f2bf_k<<<2048, 256, 0, stream>>>(conv_w, w_bf, KTOT * COUT / 4);
    f2bf_k<<<768, 256, 0, stream>>>(w_ih, wih_bf, 1536 * COUT / 4);

    dim3 cgrid(4, 64);
    conv_mfma_k<<<cgrid, 256, 0, stream>>>(input, w_bf, conv_b, conv_out);

    dim3 pgrid(12, 64);
    proj_mfma_k<<<pgrid, 256, 0, stream>>>(conv_out, wih_bf, b_ih, gi);

    // reset exchange epochs each launch (replays don't re-poison d_ws)
    hipMemsetAsync(h_ex, 0, 32768, stream);

    gru_scan_k<<<32, 512, 0, stream>>>(gi, w_hh, b_hh, hidden, out, h_ex);
}

// Round 12
// 2345.423 us; speedup vs baseline: 117.8548x; 1.2754x over previous
//
#include <hip/hip_runtime.h>
#include <hip/hip_fp16.h>
#include <hip/hip_bf16.h>

#define TSTEPS 1019
#define BATCH 8
#define CIN 4
#define LEN 524288
#define COUT 512
#define HID 512
#define KERN 3072
#define CSTRIDE 512
#define KTOT (CIN * KERN)          // 12288
#define MROWS (TSTEPS * BATCH)     // 8152

typedef _Float16 half2_v __attribute__((ext_vector_type(2)));
typedef __attribute__((ext_vector_type(8))) short bf16x8;
typedef __attribute__((ext_vector_type(4))) float f32x4;
typedef unsigned long long u64;

#if defined(__has_builtin)
#if __has_builtin(__builtin_amdgcn_fdot2)
#define HAVE_FDOT2 1
#endif
#endif

__device__ __forceinline__ float dot2f(__half2 a, __half2 b, float c) {
#ifdef HAVE_FDOT2
    return __builtin_amdgcn_fdot2(__builtin_bit_cast(half2_v, a),
                                  __builtin_bit_cast(half2_v, b), c, false);
#else
    float2 af = __half22float2(a), bf = __half22float2(b);
    return fmaf(af.y, bf.y, fmaf(af.x, bf.x, c));
#endif
}

struct __align__(16) H2x4 { __half2 x, y, z, w; };

__device__ __forceinline__ short bfc(float x) {
    return (short)__builtin_bit_cast(unsigned short, __float2bfloat16(x));
}

__device__ __forceinline__ void load_lds16(const unsigned short* g, unsigned short* l) {
    __builtin_amdgcn_global_load_lds(
        (const __attribute__((address_space(1))) void*)g,
        (__attribute__((address_space(3))) void*)l, 16, 0, 0);
}

// Publish executed AT the coherence point: fire-and-forget 64-bit atomic swap
// (no sc0 -> no return). Unlike a plain/relaxed store, the RMW cannot linger
// in the producer's write path — the value is globally visible on arrival.
__device__ __forceinline__ void pub_swap(u64* p, u64 v) {
    asm volatile("global_atomic_swap_x2 %0, %1, off" :: "v"(p), "v"(v) : "memory");
}

// ---------------------------------------------------------------------------
// fp32 -> bf16 convert (unchanged)
// ---------------------------------------------------------------------------
__global__ __launch_bounds__(256) void f2bf_k(
        const float* __restrict__ a, unsigned short* __restrict__ o, int n4) {
    int i = blockIdx.x * blockDim.x + threadIdx.x;
    int stride = gridDim.x * blockDim.x;
    for (; i < n4; i += stride) {
        float4 f = reinterpret_cast<const float4*>(a)[i];
        ushort4 u;
        u.x = (unsigned short)bfc(f.x); u.y = (unsigned short)bfc(f.y);
        u.z = (unsigned short)bfc(f.z); u.w = (unsigned short)bfc(f.w);
        reinterpret_cast<ushort4*>(o)[i] = u;
    }
}

// ---------------------------------------------------------------------------
// Conv1d implicit GEMM on MFMA (unchanged from round 4)
// ---------------------------------------------------------------------------
__global__ __launch_bounds__(256, 2) void conv_mfma_k(
        const float* __restrict__ in, const unsigned short* __restrict__ wb,
        const float* __restrict__ bias, unsigned short* __restrict__ out) {
    __shared__ unsigned short At[2][128 * 64];
    __shared__ unsigned short Bt[2][128 * 64];
    const int m0 = blockIdx.y * 128;
    const int n0 = blockIdx.x * 128;
    const int tid = threadIdx.x;
    const int w = tid >> 6, l = tid & 63;
    const int wm = w >> 1, wn = w & 1;
    const int fr = l & 15, fq = l >> 4;

    const int ra = tid >> 1, hh = tid & 1;
    int mA = m0 + ra; if (mA > MROWS - 1) mA = MROWS - 1;
    const int tA = mA >> 3, bA = mA & 7;

    f32x4 acc[4][4] = {};
    const int NT = KTOT / 64;

    {
        const float* src = in + (size_t)(bA * CIN + 0) * LEN
                              + (size_t)tA * CSTRIDE + 0 + hh * 32;
        #pragma unroll
        for (int cc = 0; cc < 4; ++cc) {
            float4 f0 = reinterpret_cast<const float4*>(src)[cc * 2];
            float4 f1 = reinterpret_cast<const float4*>(src)[cc * 2 + 1];
            bf16x8 v;
            v[0] = bfc(f0.x); v[1] = bfc(f0.y); v[2] = bfc(f0.z); v[3] = bfc(f0.w);
            v[4] = bfc(f1.x); v[5] = bfc(f1.y); v[6] = bfc(f1.z); v[7] = bfc(f1.w);
            const int c = hh * 4 + cc, s = c ^ (ra & 7);
            *reinterpret_cast<bf16x8*>(&At[0][ra * 64 + s * 8]) = v;
        }
        #pragma unroll
        for (int i = 0; i < 4; ++i) {
            const int rb = w * 32 + i * 8 + (l >> 3);
            const int s = l & 7, c = s ^ (rb & 7);
            load_lds16(wb + (size_t)(n0 + rb) * KTOT + 0 + c * 8,
                       &Bt[0][(w * 32 + i * 8) * 64]);
        }
    }
    __syncthreads();

    int cur = 0;
    for (int t = 0; t < NT; ++t) {
        const int nxt = cur ^ 1;
        float4 fA[8];
        const bool more = (t + 1 < NT);
        if (more) {
            const int k0 = (t + 1) * 64;
            const int ci = k0 / KERN, kr = k0 - ci * KERN;
            const float* src = in + (size_t)(bA * CIN + ci) * LEN
                                  + (size_t)tA * CSTRIDE + kr + hh * 32;
            #pragma unroll
            for (int v = 0; v < 8; ++v)
                fA[v] = reinterpret_cast<const float4*>(src)[v];
            #pragma unroll
            for (int i = 0; i < 4; ++i) {
                const int rb = w * 32 + i * 8 + (l >> 3);
                const int s = l & 7, c = s ^ (rb & 7);
                load_lds16(wb + (size_t)(n0 + rb) * KTOT + k0 + c * 8,
                           &Bt[nxt][(w * 32 + i * 8) * 64]);
            }
        }
        #pragma unroll
        for (int ks = 0; ks < 2; ++ks) {
            bf16x8 af[4], bfg[4];
            #pragma unroll
            for (int mf = 0; mf < 4; ++mf) {
                const int rA = wm * 64 + mf * 16 + fr;
                const int cw = ks * 4 + fq, s = cw ^ (rA & 7);
                af[mf] = *reinterpret_cast<const bf16x8*>(&At[cur][rA * 64 + s * 8]);
            }
            #pragma unroll
            for (int nf = 0; nf < 4; ++nf) {
                const int rB = wn * 64 + nf * 16 + fr;
                const int cw = ks * 4 + fq, s = cw ^ (rB & 7);
                bfg[nf] = *reinterpret_cast<const bf16x8*>(&Bt[cur][rB * 64 + s * 8]);
            }
            #pragma unroll
            for (int mf = 0; mf < 4; ++mf)
                #pragma unroll
                for (int nf = 0; nf < 4; ++nf)
                    acc[mf][nf] = __builtin_amdgcn_mfma_f32_16x16x32_bf16(
                        af[mf], bfg[nf], acc[mf][nf], 0, 0, 0);
        }
        if (more) {
            #pragma unroll
            for (int cc = 0; cc < 4; ++cc) {
                float4 f0 = fA[cc * 2], f1 = fA[cc * 2 + 1];
                bf16x8 v;
                v[0] = bfc(f0.x); v[1] = bfc(f0.y); v[2] = bfc(f0.z); v[3] = bfc(f0.w);
                v[4] = bfc(f1.x); v[5] = bfc(f1.y); v[6] = bfc(f1.z); v[7] = bfc(f1.w);
                const int c = hh * 4 + cc, s = c ^ (ra & 7);
                *reinterpret_cast<bf16x8*>(&At[nxt][ra * 64 + s * 8]) = v;
            }
        }
        __syncthreads();
        cur = nxt;
    }

    #pragma unroll
    for (int nf = 0; nf < 4; ++nf) {
        const int n = n0 + wn * 64 + nf * 16 + fr;
        const float bv = bias[n];
        #pragma unroll
        for (int mf = 0; mf < 4; ++mf) {
            #pragma unroll
            for (int i = 0; i < 4; ++i) {
                const int m = m0 + wm * 64 + mf * 16 + fq * 4 + i;
                if (m < MROWS)
                    out[(size_t)m * COUT + n] =
                        (unsigned short)bfc(acc[mf][nf][i] + bv);
            }
        }
    }
}

// ---------------------------------------------------------------------------
// gi projection MFMA (unchanged from round 4)
// ---------------------------------------------------------------------------
__global__ __launch_bounds__(256, 2) void proj_mfma_k(
        const unsigned short* __restrict__ A, const unsigned short* __restrict__ wb,
        const float* __restrict__ bias, float* __restrict__ out) {
    __shared__ unsigned short At[2][128 * 64];
    __shared__ unsigned short Bt[2][128 * 64];
    const int m0 = blockIdx.y * 128;
    const int n0 = blockIdx.x * 128;
    const int tid = threadIdx.x;
    const int w = tid >> 6, l = tid & 63;
    const int wm = w >> 1, wn = w & 1;
    const int fr = l & 15, fq = l >> 4;

    f32x4 acc[4][4] = {};
    const int NT = COUT / 64;

    auto stage = [&](int buf, int k0) {
        #pragma unroll
        for (int i = 0; i < 4; ++i) {
            const int r = w * 32 + i * 8 + (l >> 3);
            const int s = l & 7, c = s ^ (r & 7);
            int mA = m0 + r; if (mA > MROWS - 1) mA = MROWS - 1;
            load_lds16(A + (size_t)mA * COUT + k0 + c * 8,
                       &At[buf][(w * 32 + i * 8) * 64]);
            load_lds16(wb + (size_t)(n0 + r) * COUT + k0 + c * 8,
                       &Bt[buf][(w * 32 + i * 8) * 64]);
        }
    };

    stage(0, 0);
    __syncthreads();
    int cur = 0;
    for (int t = 0; t < NT; ++t) {
        const int nxt = cur ^ 1;
        if (t + 1 < NT) stage(nxt, (t + 1) * 64);
        #pragma unroll
        for (int ks = 0; ks < 2; ++ks) {
            bf16x8 af[4], bfg[4];
            #pragma unroll
            for (int mf = 0; mf < 4; ++mf) {
                const int rA = wm * 64 + mf * 16 + fr;
                const int cw = ks * 4 + fq, s = cw ^ (rA & 7);
                af[mf] = *reinterpret_cast<const bf16x8*>(&At[cur][rA * 64 + s * 8]);
            }
            #pragma unroll
            for (int nf = 0; nf < 4; ++nf) {
                const int rB = wn * 64 + nf * 16 + fr;
                const int cw = ks * 4 + fq, s = cw ^ (rB & 7);
                bfg[nf] = *reinterpret_cast<const bf16x8*>(&Bt[cur][rB * 64 + s * 8]);
            }
            #pragma unroll
            for (int mf = 0; mf < 4; ++mf)
                #pragma unroll
                for (int nf = 0; nf < 4; ++nf)
                    acc[mf][nf] = __builtin_amdgcn_mfma_f32_16x16x32_bf16(
                        af[mf], bfg[nf], acc[mf][nf], 0, 0, 0);
        }
        __syncthreads();
        cur = nxt;
    }

    #pragma unroll
    for (int nf = 0; nf < 4; ++nf) {
        const int n = n0 + wn * 64 + nf * 16 + fr;
        const float bv = bias[n];
        #pragma unroll
        for (int mf = 0; mf < 4; ++mf) {
            #pragma unroll
            for (int i = 0; i < 4; ++i) {
                const int m = m0 + wm * 64 + mf * 16 + fq * 4 + i;
                if (m < MROWS)
                    out[(size_t)m * 1536 + n] = acc[mf][nf][i] + bv;
            }
        }
    }
}

// ---------------------------------------------------------------------------
// GRU scan, round 12 = round 9 (proven, 1620 us) with ONE change:
// the publish is a fire-and-forget global_atomic_swap_x2 (executes at the
// coherence point -> immediate global visibility) instead of a relaxed
// agent-scope store (which can linger in the producer's write path).
// Poll reverted to round-9 serial form (round 11's 8-deep rolling poll
// regressed 54%: same-address outstanding loads merge in the MSHR and
// return one stale snapshot 8x).
// Everything else byte-identical to round 9; deadlock proof unchanged.
// ---------------------------------------------------------------------------
__global__ __launch_bounds__(512, 1) void gru_scan_k(
        const float* __restrict__ gi, const float* __restrict__ w_hh,
        const float* __restrict__ b_hh, const float* __restrict__ hidden,
        float* __restrict__ out, u64* __restrict__ h_ex) {
    const int bid = blockIdx.x;
    const int b   = bid & 7;           // team/batch
    const int isl = bid >> 3;          // slice: block owns rows isl*128..+128
    const int tid = threadIdx.x;
    const int wv  = tid >> 6;          // wave 0..7
    const int l   = tid & 63;
    const int q   = wv >> 1;           // k-quarter this wave-pair consumes
    const int g   = (wv & 1) * 64 + l; // row-in-block 0..127
    const int j   = isl * 128 + g;     // h row this thread computes (quarter q)
    const bool is_gate = (q == isl);

    __shared__ __align__(16) __half2 strip[8][64];  // per-wave h-quarter copy
    __shared__ float p_lds[3 * 128 * 5];            // partials, stride 5
    __shared__ int lflag[2];                        // gate-wave epoch flags

    // weights: 3 gates x 128 k (quarter q) of row j -> 192 half2
    __half2 wreg[3][64];
    #pragma unroll
    for (int m = 0; m < 3; ++m) {
        const float* wp = w_hh + (size_t)(j + m * 512) * HID + q * 128;
        #pragma unroll
        for (int kk = 0; kk < 32; ++kk) {
            float4 v = reinterpret_cast<const float4*>(wp)[kk];
            wreg[m][2 * kk]     = __halves2half2(__float2half_rn(v.x), __float2half_rn(v.y));
            wreg[m][2 * kk + 1] = __halves2half2(__float2half_rn(v.z), __float2half_rn(v.w));
        }
    }

    float bhr = 0.f, bhz = 0.f, bhn = 0.f, hprev = 0.f;
    float gir = 0.f, giz = 0.f, gin = 0.f;
    if (is_gate) {
        bhr = b_hh[j]; bhz = b_hh[j + 512]; bhn = b_hh[j + 1024];
        hprev = hidden[b * HID + j];
        gir = gi[(size_t)b * 1536 + j];
        giz = gi[(size_t)b * 1536 + j + 512];
        gin = gi[(size_t)b * 1536 + j + 1024];
    }
    if (tid < 2) lflag[tid] = 0;
    // prologue: every wave fills its own strip with h_0 (epoch 0, local)
    strip[wv][l] = __halves2half2(__float2half(hidden[b * HID + q * 128 + 2 * l]),
                                  __float2half(hidden[b * HID + q * 128 + 2 * l + 1]));
    __syncthreads();

    for (int t = 0; t < TSTEPS; ++t) {
        // ---- acquire epoch t (t>0): pair-owned, no cross-wave sync ----
        if (t > 0) {
            if (!is_gate) {
                const u64* src =
                    h_ex + (size_t)((t & 1) * BATCH + b) * 256 + q * 64 + l;
                u64 v;
                do {
                    v = __hip_atomic_load(src, __ATOMIC_RELAXED,
                                          __HIP_MEMORY_SCOPE_AGENT);
                } while ((unsigned)(v >> 32) != (unsigned)t);
                strip[wv][l] =
                    __builtin_bit_cast(__half2, (unsigned)(v & 0xffffffffu));
                asm volatile("s_waitcnt lgkmcnt(0)" ::: "memory");
            } else {
                volatile int* f0 = &lflag[0];
                volatile int* f1 = &lflag[1];
                while (*f0 < t || *f1 < t) {}
                asm volatile("" ::: "memory");
            }
        }
        // ---- matvec over quarter q from the wave's strip (broadcast b128) ----
        const H2x4* hv4 = reinterpret_cast<const H2x4*>(&strip[wv][0]);
        float a0 = 0, a1 = 0, a2 = 0, c0 = 0, c1 = 0, c2 = 0;
        #pragma unroll
        for (int kk = 0; kk < 16; ++kk) {
            H2x4 h4 = hv4[kk];
            a0 = dot2f(wreg[0][4 * kk + 0], h4.x, a0);
            a1 = dot2f(wreg[1][4 * kk + 0], h4.x, a1);
            a2 = dot2f(wreg[2][4 * kk + 0], h4.x, a2);
            c0 = dot2f(wreg[0][4 * kk + 1], h4.y, c0);
            c1 = dot2f(wreg[1][4 * kk + 1], h4.y, c1);
            c2 = dot2f(wreg[2][4 * kk + 1], h4.y, c2);
            a0 = dot2f(wreg[0][4 * kk + 2], h4.z, a0);
            a1 = dot2f(wreg[1][4 * kk + 2], h4.z, a1);
            a2 = dot2f(wreg[2][4 * kk + 2], h4.z, a2);
            c0 = dot2f(wreg[0][4 * kk + 3], h4.w, c0);
            c1 = dot2f(wreg[1][4 * kk + 3], h4.w, c1);
            c2 = dot2f(wreg[2][4 * kk + 3], h4.w, c2);
        }
        p_lds[(0 * 128 + g) * 5 + q] = a0 + c0;   // stride 5: conflict-free
        p_lds[(1 * 128 + g) * 5 + q] = a1 + c1;
        p_lds[(2 * 128 + g) * 5 + q] = a2 + c2;
        __syncthreads();   // B1 (the ONLY barrier per step)

        // ---- gates by pair isl; remote pairs fall through and poll t+1 ----
        if (is_gate) {
            const float* pr = &p_lds[(0 * 128 + g) * 5];
            const float* pz = &p_lds[(1 * 128 + g) * 5];
            const float* pn = &p_lds[(2 * 128 + g) * 5];
            const float ghr = (pr[0] + pr[1]) + (pr[2] + pr[3]) + bhr;
            const float ghz = (pz[0] + pz[1]) + (pz[2] + pz[3]) + bhz;
            const float ghn = (pn[0] + pn[1]) + (pn[2] + pn[3]) + bhn;
            const float rr = 1.f / (1.f + __expf(-(gir + ghr)));
            const float zz = 1.f / (1.f + __expf(-(giz + ghz)));
            const float nx = gin + rr * ghn;
            const float nn = 1.f - 2.f / (__expf(2.f * nx) + 1.f);   // tanh
            const float hnew = (1.f - zz) * nn + zz * hprev;
            hprev = hnew;
            const float hother = __shfl_xor(hnew, 1);
            if (t + 1 < TSTEPS) {
                if (!(g & 1)) {
                    const __half2 h2 = __halves2half2(__float2half(hnew),
                                                      __float2half(hother));
                    const u64 v =
                        ((u64)(unsigned)(t + 1) << 32) |
                        (u64)__builtin_bit_cast(unsigned, h2);
                    // publish at the coherence point (fire-and-forget RMW)
                    pub_swap(h_ex + (size_t)(((t + 1) & 1) * BATCH + b) * 256
                                  + isl * 64 + (g >> 1), v);
                    // local handoff for next step's own-quarter matvec
                    strip[2 * isl][g >> 1] = h2;
                    strip[2 * isl + 1][g >> 1] = h2;
                }
                asm volatile("s_waitcnt lgkmcnt(0)" ::: "memory");
                if (l == 0) lflag[wv & 1] = t + 1;   // per-gate-wave flag
                out[(size_t)(t * BATCH + b) * HID + j] = hnew;
                const float* gp = gi + (size_t)((t + 1) * BATCH + b) * 1536 + j;
                gir = gp[0]; giz = gp[512]; gin = gp[1024];
            } else {
                out[(size_t)(t * BATCH + b) * HID + j] = hnew;
            }
        }
        // no second barrier: see header comment for the anti-hazard proof
    }
    if (is_gate)
        out[(size_t)TSTEPS * BATCH * HID + b * HID + j] = hprev;
}

extern "C" void kernel_launch(void* const* d_in, const int* in_sizes, int n_in,
                              void* d_out, int out_size, void* d_ws, size_t ws_size,
                              hipStream_t stream) {
    (void)in_sizes; (void)n_in; (void)out_size; (void)ws_size;
    const float* input  = (const float*)d_in[0];
    const float* hidden = (const float*)d_in[1];
    const float* conv_w = (const float*)d_in[2];
    const float* conv_b = (const float*)d_in[3];
    const float* w_ih   = (const float*)d_in[4];
    const float* w_hh   = (const float*)d_in[5];
    const float* b_ih   = (const float*)d_in[6];
    const float* b_hh   = (const float*)d_in[7];
    float* out = (float*)d_out;

    char* ws = (char*)d_ws;
    float*          gi       = (float*)ws;                          // 50,085,888 B
    unsigned short* conv_out = (unsigned short*)(ws + 50085888);    //  8,347,648 B
    unsigned short* w_bf     = (unsigned short*)(ws + 58433536);    // 12,582,912 B
    unsigned short* wih_bf   = (unsigned short*)(ws + 71016448);    //  1,572,864 B
    u64*            h_ex     = (u64*)(ws + 72589312);               //     32,768 B

    f2bf_k<<<2048, 256, 0, stream>>>(conv_w, w_bf, KTOT * COUT / 4);
    f2bf_k<<<768, 256, 0, stream>>>(w_ih, wih_bf, 1536 * COUT / 4);

    dim3 cgrid(4, 64);
    conv_mfma_k<<<cgrid, 256, 0, stream>>>(input, w_bf, conv_b, conv_out);

    dim3 pgrid(12, 64);
    proj_mfma_k<<<pgrid, 256, 0, stream>>>(conv_out, wih_bf, b_ih, gi);

    // reset exchange epochs each launch (replays don't re-poison d_ws)
    hipMemsetAsync(h_ex, 0, 32768, stream);

    gru_scan_k<<<32, 512, 0, stream>>>(gi, w_hh, b_hh, hidden, out, h_ex);
}

// Round 13
// 2116.876 us; speedup vs baseline: 130.5789x; 1.1080x over previous
//
#include <hip/hip_runtime.h>
#include <hip/hip_fp16.h>
#include <hip/hip_bf16.h>

#define TSTEPS 1019
#define BATCH 8
#define CIN 4
#define LEN 524288
#define COUT 512
#define HID 512
#define KERN 3072
#define CSTRIDE 512
#define KTOT (CIN * KERN)          // 12288
#define MROWS (TSTEPS * BATCH)     // 8152

typedef _Float16 half2_v __attribute__((ext_vector_type(2)));
typedef __attribute__((ext_vector_type(8))) short bf16x8;
typedef __attribute__((ext_vector_type(4))) float f32x4;
typedef unsigned long long u64;

#if defined(__has_builtin)
#if __has_builtin(__builtin_amdgcn_fdot2)
#define HAVE_FDOT2 1
#endif
#endif

__device__ __forceinline__ float dot2f(__half2 a, __half2 b, float c) {
#ifdef HAVE_FDOT2
    return __builtin_amdgcn_fdot2(__builtin_bit_cast(half2_v, a),
                                  __builtin_bit_cast(half2_v, b), c, false);
#else
    float2 af = __half22float2(a), bf = __half22float2(b);
    return fmaf(af.y, bf.y, fmaf(af.x, bf.x, c));
#endif
}

struct __align__(16) H2x4 { __half2 x, y, z, w; };

__device__ __forceinline__ short bfc(float x) {
    return (short)__builtin_bit_cast(unsigned short, __float2bfloat16(x));
}

__device__ __forceinline__ void load_lds16(const unsigned short* g, unsigned short* l) {
    __builtin_amdgcn_global_load_lds(
        (const __attribute__((address_space(1))) void*)g,
        (__attribute__((address_space(3))) void*)l, 16, 0, 0);
}

// ---------------------------------------------------------------------------
// fp32 -> bf16 convert (unchanged)
// ---------------------------------------------------------------------------
__global__ __launch_bounds__(256) void f2bf_k(
        const float* __restrict__ a, unsigned short* __restrict__ o, int n4) {
    int i = blockIdx.x * blockDim.x + threadIdx.x;
    int stride = gridDim.x * blockDim.x;
    for (; i < n4; i += stride) {
        float4 f = reinterpret_cast<const float4*>(a)[i];
        ushort4 u;
        u.x = (unsigned short)bfc(f.x); u.y = (unsigned short)bfc(f.y);
        u.z = (unsigned short)bfc(f.z); u.w = (unsigned short)bfc(f.w);
        reinterpret_cast<ushort4*>(o)[i] = u;
    }
}

// ---------------------------------------------------------------------------
// Conv1d implicit GEMM on MFMA (unchanged from round 4)
// ---------------------------------------------------------------------------
__global__ __launch_bounds__(256, 2) void conv_mfma_k(
        const float* __restrict__ in, const unsigned short* __restrict__ wb,
        const float* __restrict__ bias, unsigned short* __restrict__ out) {
    __shared__ unsigned short At[2][128 * 64];
    __shared__ unsigned short Bt[2][128 * 64];
    const int m0 = blockIdx.y * 128;
    const int n0 = blockIdx.x * 128;
    const int tid = threadIdx.x;
    const int w = tid >> 6, l = tid & 63;
    const int wm = w >> 1, wn = w & 1;
    const int fr = l & 15, fq = l >> 4;

    const int ra = tid >> 1, hh = tid & 1;
    int mA = m0 + ra; if (mA > MROWS - 1) mA = MROWS - 1;
    const int tA = mA >> 3, bA = mA & 7;

    f32x4 acc[4][4] = {};
    const int NT = KTOT / 64;

    {
        const float* src = in + (size_t)(bA * CIN + 0) * LEN
                              + (size_t)tA * CSTRIDE + 0 + hh * 32;
        #pragma unroll
        for (int cc = 0; cc < 4; ++cc) {
            float4 f0 = reinterpret_cast<const float4*>(src)[cc * 2];
            float4 f1 = reinterpret_cast<const float4*>(src)[cc * 2 + 1];
            bf16x8 v;
            v[0] = bfc(f0.x); v[1] = bfc(f0.y); v[2] = bfc(f0.z); v[3] = bfc(f0.w);
            v[4] = bfc(f1.x); v[5] = bfc(f1.y); v[6] = bfc(f1.z); v[7] = bfc(f1.w);
            const int c = hh * 4 + cc, s = c ^ (ra & 7);
            *reinterpret_cast<bf16x8*>(&At[0][ra * 64 + s * 8]) = v;
        }
        #pragma unroll
        for (int i = 0; i < 4; ++i) {
            const int rb = w * 32 + i * 8 + (l >> 3);
            const int s = l & 7, c = s ^ (rb & 7);
            load_lds16(wb + (size_t)(n0 + rb) * KTOT + 0 + c * 8,
                       &Bt[0][(w * 32 + i * 8) * 64]);
        }
    }
    __syncthreads();

    int cur = 0;
    for (int t = 0; t < NT; ++t) {
        const int nxt = cur ^ 1;
        float4 fA[8];
        const bool more = (t + 1 < NT);
        if (more) {
            const int k0 = (t + 1) * 64;
            const int ci = k0 / KERN, kr = k0 - ci * KERN;
            const float* src = in + (size_t)(bA * CIN + ci) * LEN
                                  + (size_t)tA * CSTRIDE + kr + hh * 32;
            #pragma unroll
            for (int v = 0; v < 8; ++v)
                fA[v] = reinterpret_cast<const float4*>(src)[v];
            #pragma unroll
            for (int i = 0; i < 4; ++i) {
                const int rb = w * 32 + i * 8 + (l >> 3);
                const int s = l & 7, c = s ^ (rb & 7);
                load_lds16(wb + (size_t)(n0 + rb) * KTOT + k0 + c * 8,
                           &Bt[nxt][(w * 32 + i * 8) * 64]);
            }
        }
        #pragma unroll
        for (int ks = 0; ks < 2; ++ks) {
            bf16x8 af[4], bfg[4];
            #pragma unroll
            for (int mf = 0; mf < 4; ++mf) {
                const int rA = wm * 64 + mf * 16 + fr;
                const int cw = ks * 4 + fq, s = cw ^ (rA & 7);
                af[mf] = *reinterpret_cast<const bf16x8*>(&At[cur][rA * 64 + s * 8]);
            }
            #pragma unroll
            for (int nf = 0; nf < 4; ++nf) {
                const int rB = wn * 64 + nf * 16 + fr;
                const int cw = ks * 4 + fq, s = cw ^ (rB & 7);
                bfg[nf] = *reinterpret_cast<const bf16x8*>(&Bt[cur][rB * 64 + s * 8]);
            }
            #pragma unroll
            for (int mf = 0; mf < 4; ++mf)
                #pragma unroll
                for (int nf = 0; nf < 4; ++nf)
                    acc[mf][nf] = __builtin_amdgcn_mfma_f32_16x16x32_bf16(
                        af[mf], bfg[nf], acc[mf][nf], 0, 0, 0);
        }
        if (more) {
            #pragma unroll
            for (int cc = 0; cc < 4; ++cc) {
                float4 f0 = fA[cc * 2], f1 = fA[cc * 2 + 1];
                bf16x8 v;
                v[0] = bfc(f0.x); v[1] = bfc(f0.y); v[2] = bfc(f0.z); v[3] = bfc(f0.w);
                v[4] = bfc(f1.x); v[5] = bfc(f1.y); v[6] = bfc(f1.z); v[7] = bfc(f1.w);
                const int c = hh * 4 + cc, s = c ^ (ra & 7);
                *reinterpret_cast<bf16x8*>(&At[nxt][ra * 64 + s * 8]) = v;
            }
        }
        __syncthreads();
        cur = nxt;
    }

    #pragma unroll
    for (int nf = 0; nf < 4; ++nf) {
        const int n = n0 + wn * 64 + nf * 16 + fr;
        const float bv = bias[n];
        #pragma unroll
        for (int mf = 0; mf < 4; ++mf) {
            #pragma unroll
            for (int i = 0; i < 4; ++i) {
                const int m = m0 + wm * 64 + mf * 16 + fq * 4 + i;
                if (m < MROWS)
                    out[(size_t)m * COUT + n] =
                        (unsigned short)bfc(acc[mf][nf][i] + bv);
            }
        }
    }
}

// ---------------------------------------------------------------------------
// gi projection MFMA (unchanged from round 4)
// ---------------------------------------------------------------------------
__global__ __launch_bounds__(256, 2) void proj_mfma_k(
        const unsigned short* __restrict__ A, const unsigned short* __restrict__ wb,
        const float* __restrict__ bias, float* __restrict__ out) {
    __shared__ unsigned short At[2][128 * 64];
    __shared__ unsigned short Bt[2][128 * 64];
    const int m0 = blockIdx.y * 128;
    const int n0 = blockIdx.x * 128;
    const int tid = threadIdx.x;
    const int w = tid >> 6, l = tid & 63;
    const int wm = w >> 1, wn = w & 1;
    const int fr = l & 15, fq = l >> 4;

    f32x4 acc[4][4] = {};
    const int NT = COUT / 64;

    auto stage = [&](int buf, int k0) {
        #pragma unroll
        for (int i = 0; i < 4; ++i) {
            const int r = w * 32 + i * 8 + (l >> 3);
            const int s = l & 7, c = s ^ (r & 7);
            int mA = m0 + r; if (mA > MROWS - 1) mA = MROWS - 1;
            load_lds16(A + (size_t)mA * COUT + k0 + c * 8,
                       &At[buf][(w * 32 + i * 8) * 64]);
            load_lds16(wb + (size_t)(n0 + r) * COUT + k0 + c * 8,
                       &Bt[buf][(w * 32 + i * 8) * 64]);
        }
    };

    stage(0, 0);
    __syncthreads();
    int cur = 0;
    for (int t = 0; t < NT; ++t) {
        const int nxt = cur ^ 1;
        if (t + 1 < NT) stage(nxt, (t + 1) * 64);
        #pragma unroll
        for (int ks = 0; ks < 2; ++ks) {
            bf16x8 af[4], bfg[4];
            #pragma unroll
            for (int mf = 0; mf < 4; ++mf) {
                const int rA = wm * 64 + mf * 16 + fr;
                const int cw = ks * 4 + fq, s = cw ^ (rA & 7);
                af[mf] = *reinterpret_cast<const bf16x8*>(&At[cur][rA * 64 + s * 8]);
            }
            #pragma unroll
            for (int nf = 0; nf < 4; ++nf) {
                const int rB = wn * 64 + nf * 16 + fr;
                const int cw = ks * 4 + fq, s = cw ^ (rB & 7);
                bfg[nf] = *reinterpret_cast<const bf16x8*>(&Bt[cur][rB * 64 + s * 8]);
            }
            #pragma unroll
            for (int mf = 0; mf < 4; ++mf)
                #pragma unroll
                for (int nf = 0; nf < 4; ++nf)
                    acc[mf][nf] = __builtin_amdgcn_mfma_f32_16x16x32_bf16(
                        af[mf], bfg[nf], acc[mf][nf], 0, 0, 0);
        }
        __syncthreads();
        cur = nxt;
    }

    #pragma unroll
    for (int nf = 0; nf < 4; ++nf) {
        const int n = n0 + wn * 64 + nf * 16 + fr;
        const float bv = bias[n];
        #pragma unroll
        for (int mf = 0; mf < 4; ++mf) {
            #pragma unroll
            for (int i = 0; i < 4; ++i) {
                const int m = m0 + wm * 64 + mf * 16 + fq * 4 + i;
                if (m < MROWS)
                    out[(size_t)m * 1536 + n] = acc[mf][nf][i] + bv;
            }
        }
    }
}

// ---------------------------------------------------------------------------
// GRU scan, round 13 = round 9 byte-exact (best: scan 1620 us, total 2129;
// pub_swap reverted — round 12 proved publish visibility is not a term) plus
// ONE change: amdgpu_waves_per_eu(1,2). Round 9/12 reported VGPR_Count=128
// for a kernel whose wreg array alone needs 192 regs -> the allocator split
// weights into AGPRs (unified file), adding a v_accvgpr_read per dot2 and
// roughly doubling matvec issue. Only 32 of 256 CUs are used, so occupancy
// is worthless: telling the compiler max-2-waves/EU is fine lifts the arch-
// VGPR cap to 256 and keeps wreg VGPR-resident.
// Protocol unchanged (round-3 proof): relaxed agent-scope store of
// {epoch:32|2xfp16:32}, exact-epoch serial poll, parity double-buffer;
// single barrier per step; pair-owned quarters.
// ---------------------------------------------------------------------------
__global__ __launch_bounds__(512)
__attribute__((amdgpu_waves_per_eu(1, 2)))
void gru_scan_k(
        const float* __restrict__ gi, const float* __restrict__ w_hh,
        const float* __restrict__ b_hh, const float* __restrict__ hidden,
        float* __restrict__ out, u64* __restrict__ h_ex) {
    const int bid = blockIdx.x;
    const int b   = bid & 7;           // team/batch
    const int isl = bid >> 3;          // slice: block owns rows isl*128..+128
    const int tid = threadIdx.x;
    const int wv  = tid >> 6;          // wave 0..7
    const int l   = tid & 63;
    const int q   = wv >> 1;           // k-quarter this wave-pair consumes
    const int g   = (wv & 1) * 64 + l; // row-in-block 0..127
    const int j   = isl * 128 + g;     // h row this thread computes (quarter q)
    const bool is_gate = (q == isl);

    __shared__ __align__(16) __half2 strip[8][64];  // per-wave h-quarter copy
    __shared__ float p_lds[3 * 128 * 5];            // partials, stride 5
    __shared__ int lflag[2];                        // gate-wave epoch flags

    // weights: 3 gates x 128 k (quarter q) of row j -> 192 half2
    __half2 wreg[3][64];
    #pragma unroll
    for (int m = 0; m < 3; ++m) {
        const float* wp = w_hh + (size_t)(j + m * 512) * HID + q * 128;
        #pragma unroll
        for (int kk = 0; kk < 32; ++kk) {
            float4 v = reinterpret_cast<const float4*>(wp)[kk];
            wreg[m][2 * kk]     = __halves2half2(__float2half_rn(v.x), __float2half_rn(v.y));
            wreg[m][2 * kk + 1] = __halves2half2(__float2half_rn(v.z), __float2half_rn(v.w));
        }
    }

    float bhr = 0.f, bhz = 0.f, bhn = 0.f, hprev = 0.f;
    float gir = 0.f, giz = 0.f, gin = 0.f;
    if (is_gate) {
        bhr = b_hh[j]; bhz = b_hh[j + 512]; bhn = b_hh[j + 1024];
        hprev = hidden[b * HID + j];
        gir = gi[(size_t)b * 1536 + j];
        giz = gi[(size_t)b * 1536 + j + 512];
        gin = gi[(size_t)b * 1536 + j + 1024];
    }
    if (tid < 2) lflag[tid] = 0;
    // prologue: every wave fills its own strip with h_0 (epoch 0, local)
    strip[wv][l] = __halves2half2(__float2half(hidden[b * HID + q * 128 + 2 * l]),
                                  __float2half(hidden[b * HID + q * 128 + 2 * l + 1]));
    __syncthreads();

    for (int t = 0; t < TSTEPS; ++t) {
        // ---- acquire epoch t (t>0): pair-owned, no cross-wave sync ----
        if (t > 0) {
            if (!is_gate) {
                const u64* src =
                    h_ex + (size_t)((t & 1) * BATCH + b) * 256 + q * 64 + l;
                u64 v;
                do {
                    v = __hip_atomic_load(src, __ATOMIC_RELAXED,
                                          __HIP_MEMORY_SCOPE_AGENT);
                } while ((unsigned)(v >> 32) != (unsigned)t);
                strip[wv][l] =
                    __builtin_bit_cast(__half2, (unsigned)(v & 0xffffffffu));
                asm volatile("s_waitcnt lgkmcnt(0)" ::: "memory");
            } else {
                volatile int* f0 = &lflag[0];
                volatile int* f1 = &lflag[1];
                while (*f0 < t || *f1 < t) {}
                asm volatile("" ::: "memory");
            }
        }
        // ---- matvec over quarter q from the wave's strip (broadcast b128) ----
        const H2x4* hv4 = reinterpret_cast<const H2x4*>(&strip[wv][0]);
        float a0 = 0, a1 = 0, a2 = 0, c0 = 0, c1 = 0, c2 = 0;
        #pragma unroll
        for (int kk = 0; kk < 16; ++kk) {
            H2x4 h4 = hv4[kk];
            a0 = dot2f(wreg[0][4 * kk + 0], h4.x, a0);
            a1 = dot2f(wreg[1][4 * kk + 0], h4.x, a1);
            a2 = dot2f(wreg[2][4 * kk + 0], h4.x, a2);
            c0 = dot2f(wreg[0][4 * kk + 1], h4.y, c0);
            c1 = dot2f(wreg[1][4 * kk + 1], h4.y, c1);
            c2 = dot2f(wreg[2][4 * kk + 1], h4.y, c2);
            a0 = dot2f(wreg[0][4 * kk + 2], h4.z, a0);
            a1 = dot2f(wreg[1][4 * kk + 2], h4.z, a1);
            a2 = dot2f(wreg[2][4 * kk + 2], h4.z, a2);
            c0 = dot2f(wreg[0][4 * kk + 3], h4.w, c0);
            c1 = dot2f(wreg[1][4 * kk + 3], h4.w, c1);
            c2 = dot2f(wreg[2][4 * kk + 3], h4.w, c2);
        }
        p_lds[(0 * 128 + g) * 5 + q] = a0 + c0;   // stride 5: conflict-free
        p_lds[(1 * 128 + g) * 5 + q] = a1 + c1;
        p_lds[(2 * 128 + g) * 5 + q] = a2 + c2;
        __syncthreads();   // B1 (the ONLY barrier per step)

        // ---- gates by pair isl; remote pairs fall through and poll t+1 ----
        if (is_gate) {
            const float* pr = &p_lds[(0 * 128 + g) * 5];
            const float* pz = &p_lds[(1 * 128 + g) * 5];
            const float* pn = &p_lds[(2 * 128 + g) * 5];
            const float ghr = (pr[0] + pr[1]) + (pr[2] + pr[3]) + bhr;
            const float ghz = (pz[0] + pz[1]) + (pz[2] + pz[3]) + bhz;
            const float ghn = (pn[0] + pn[1]) + (pn[2] + pn[3]) + bhn;
            const float rr = 1.f / (1.f + __expf(-(gir + ghr)));
            const float zz = 1.f / (1.f + __expf(-(giz + ghz)));
            const float nx = gin + rr * ghn;
            const float nn = 1.f - 2.f / (__expf(2.f * nx) + 1.f);   // tanh
            const float hnew = (1.f - zz) * nn + zz * hprev;
            hprev = hnew;
            const float hother = __shfl_xor(hnew, 1);
            if (t + 1 < TSTEPS) {
                if (!(g & 1)) {
                    const __half2 h2 = __halves2half2(__float2half(hnew),
                                                      __float2half(hother));
                    const u64 v =
                        ((u64)(unsigned)(t + 1) << 32) |
                        (u64)__builtin_bit_cast(unsigned, h2);
                    // publish first (remote consumers' RT is the bottleneck)
                    __hip_atomic_store(
                        h_ex + (size_t)(((t + 1) & 1) * BATCH + b) * 256
                             + isl * 64 + (g >> 1),
                        v, __ATOMIC_RELAXED, __HIP_MEMORY_SCOPE_AGENT);
                    // local handoff for next step's own-quarter matvec
                    strip[2 * isl][g >> 1] = h2;
                    strip[2 * isl + 1][g >> 1] = h2;
                }
                asm volatile("s_waitcnt lgkmcnt(0)" ::: "memory");
                if (l == 0) lflag[wv & 1] = t + 1;   // per-gate-wave flag
                out[(size_t)(t * BATCH + b) * HID + j] = hnew;
                const float* gp = gi + (size_t)((t + 1) * BATCH + b) * 1536 + j;
                gir = gp[0]; giz = gp[512]; gin = gp[1024];
            } else {
                out[(size_t)(t * BATCH + b) * HID + j] = hnew;
            }
        }
        // no second barrier: see header comment for the anti-hazard proof
    }
    if (is_gate)
        out[(size_t)TSTEPS * BATCH * HID + b * HID + j] = hprev;
}

extern "C" void kernel_launch(void* const* d_in, const int* in_sizes, int n_in,
                              void* d_out, int out_size, void* d_ws, size_t ws_size,
                              hipStream_t stream) {
    (void)in_sizes; (void)n_in; (void)out_size; (void)ws_size;
    const float* input  = (const float*)d_in[0];
    const float* hidden = (const float*)d_in[1];
    const float* conv_w = (const float*)d_in[2];
    const float* conv_b = (const float*)d_in[3];
    const float* w_ih   = (const float*)d_in[4];
    const float* w_hh   = (const float*)d_in[5];
    const float* b_ih   = (const float*)d_in[6];
    const float* b_hh   = (const float*)d_in[7];
    float* out = (float*)d_out;

    char* ws = (char*)d_ws;
    float*          gi       = (float*)ws;                          // 50,085,888 B
    unsigned short* conv_out = (unsigned short*)(ws + 50085888);    //  8,347,648 B
    unsigned short* w_bf     = (unsigned short*)(ws + 58433536);    // 12,582,912 B
    unsigned short* wih_bf   = (unsigned short*)(ws + 71016448);    //  1,572,864 B
    u64*            h_ex     = (u64*)(ws + 72589312);               //     32,768 B

    f2bf_k<<<2048, 256, 0, stream>>>(conv_w, w_bf, KTOT * COUT / 4);
    f2bf_k<<<768, 256, 0, stream>>>(w_ih, wih_bf, 1536 * COUT / 4);

    dim3 cgrid(4, 64);
    conv_mfma_k<<<cgrid, 256, 0, stream>>>(input, w_bf, conv_b, conv_out);

    dim3 pgrid(12, 64);
    proj_mfma_k<<<pgrid, 256, 0, stream>>>(conv_out, wih_bf, b_ih, gi);

    // reset exchange epochs each launch (replays don't re-poison d_ws)
    hipMemsetAsync(h_ex, 0, 32768, stream);

    gru_scan_k<<<32, 512, 0, stream>>>(gi, w_hh, b_hh, hidden, out, h_ex);
}